// Round 3
// baseline (370.494 us; speedup 1.0000x reference)
//
#include <hip/hip_runtime.h>
#include <hip/hip_bf16.h>

// RoutingLayer: B=128,S=64,N=32, inp_d=D=128, K=8 capsules x C=16, 3 routing iters.
// Inputs are fp32 (confirmed by R1-vs-R2 behavior). Split-bf16 MFMA GEMM
// (x = hi + lo, compute hi*hi + hi*lo + lo*hi) for near-fp32 precision at MFMA
// speed. Runtime dtype dispatch kept as a safety net (bf16 data -> lo = 0).

#define NB 32
#define DD 128
#define ZSTRIDE 132  // padded fp32 row stride for zn in LDS

typedef __attribute__((ext_vector_type(8))) short bf16x8;  // MFMA A/B frag
typedef __attribute__((ext_vector_type(4))) float f32x4;   // MFMA C/D frag
typedef __attribute__((ext_vector_type(4))) float float4v;

__device__ __forceinline__ float bf16bits_to_f32(unsigned short u) {
  return __uint_as_float(((unsigned int)u) << 16);
}

// Split fp32 -> (hi, lo) bf16 bits, truncation-based (exact remainder capture).
__device__ __forceinline__ void split_bf16(float x, short& hi, short& lo) {
  unsigned int xb = __float_as_uint(x);
  hi = (short)(xb >> 16);
  float hif = __uint_as_float(xb & 0xFFFF0000u);
  float lof = x - hif;  // exact
  lo = (short)(__float_as_uint(lof) >> 16);
}

// ---- dtype detection: fp32 arrays read as 16-bit words contain garbage-exponent halves ----
__global__ void detect_kernel(const unsigned short* __restrict__ w1u,
                              int* __restrict__ flag) {
  int t = threadIdx.x;  // 64 threads
  float v = bf16bits_to_f32(w1u[2 * t]);
  int hit = !(fabsf(v) < 1e4f);  // huge / inf / NaN => fp32 data
  unsigned long long m = __ballot(hit);
  if (t == 0) flag[0] = (m != 0ull) ? 1 : 0;
}

// Pre-swizzle W (k-major 128x128) into MFMA-B fragment-major hi/lo bf16:
// (k,n): kt=k>>5, q=(k>>3)&3, j=k&7, nt=n>>4, nl=n&15, lane=q*16+nl
// dst = ((kt*8+nt)*64 + lane)*8 + j
__global__ __launch_bounds__(256) void swizzle_w_kernel(
    const void* __restrict__ w1, const int* __restrict__ flag,
    unsigned short* __restrict__ whi, unsigned short* __restrict__ wlo) {
  int idx = blockIdx.x * 256 + threadIdx.x;  // 16384 elements
  int k = idx >> 7, n = idx & 127;
  int kt = k >> 5, q = (k >> 3) & 3, j = k & 7;
  int nt = n >> 4, nl = n & 15;
  int lane = q * 16 + nl;
  int dst = ((kt * 8 + nt) * 64 + lane) * 8 + j;
  short hb, lb;
  if (*flag) {
    split_bf16(((const float*)w1)[idx], hb, lb);
  } else {
    hb = (short)((const unsigned short*)w1)[idx];
    lb = 0;
  }
  whi[dst] = (unsigned short)hb;
  wlo[dst] = (unsigned short)lb;
}

__device__ __forceinline__ void load_frag2(const void* base, size_t elt_off,
                                           bool isf32, bf16x8& hi, bf16x8& lo) {
  if (!isf32) {
    hi = *(const bf16x8*)((const unsigned short*)base + elt_off);
#pragma unroll
    for (int i = 0; i < 8; ++i) lo[i] = 0;
    return;
  }
  const float* p = (const float*)base + elt_off;
  float4v v0 = *(const float4v*)p;
  float4v v1 = *(const float4v*)(p + 4);
#pragma unroll
  for (int i = 0; i < 4; ++i) {
    short h, l;
    split_bf16(v0[i], h, l);
    hi[i] = h; lo[i] = l;
    split_bf16(v1[i], h, l);
    hi[4 + i] = h; lo[4 + i] = l;
  }
}

__global__ __launch_bounds__(256) void routing_kernel(
    const void* __restrict__ selfv,   // [8192,128]
    const void* __restrict__ neighv,  // [8192,32,128]
    const unsigned short* __restrict__ whi,  // swizzled W hi bf16
    const unsigned short* __restrict__ wlo,  // swizzled W lo bf16
    const void* __restrict__ b1,      // [128]
    void* __restrict__ out,           // [8192,128]
    const int* __restrict__ flag) {
  __shared__ float zn[33 * ZSTRIDE];  // normalized capsules: rows 0..31 neigh, 32 self
  __shared__ float pl[256];           // routing logits / probs [n*8+k]

  const int tid = threadIdx.x;
  const int lane = tid & 63;
  const int wv = tid >> 6;
  const int q = lane >> 4;
  const int ml = lane & 15;
  const size_t bs = blockIdx.x;
  const bool isf32 = (*flag != 0);  // uniform scalar branch

  const size_t noff = bs * (size_t)(NB * DD);
  const size_t soff = bs * (size_t)DD;
  const char* nbase = isf32 ? (const char*)((const float*)neighv + noff)
                            : (const char*)((const unsigned short*)neighv + noff);
  const char* sbase = isf32 ? (const char*)((const float*)selfv + soff)
                            : (const char*)((const unsigned short*)selfv + soff);

  // ---------------- GEMM: Z[48x128] = X[48x128] @ W[128x128], split-bf16 -------
  f32x4 acc[3][2];
#pragma unroll
  for (int mt = 0; mt < 3; ++mt)
#pragma unroll
    for (int jn = 0; jn < 2; ++jn) acc[mt][jn] = (f32x4){0.f, 0.f, 0.f, 0.f};

  const int nt0 = wv, nt1 = wv + 4;

#pragma unroll
  for (int kt = 0; kt < 4; ++kt) {
    const int koff = kt * 32 + q * 8;
    bf16x8 a0h, a0l, a1h, a1l, a2h, a2l;
    load_frag2(nbase, (size_t)ml * DD + koff, isf32, a0h, a0l);
    load_frag2(nbase, (size_t)(16 + ml) * DD + koff, isf32, a1h, a1l);
    load_frag2(sbase, (size_t)koff, isf32, a2h, a2l);  // all lanes same row (self)
    const size_t bo0 = ((size_t)(kt * 8 + nt0) * 64 + lane) * 8;
    const size_t bo1 = ((size_t)(kt * 8 + nt1) * 64 + lane) * 8;
    bf16x8 b0h = *(const bf16x8*)(whi + bo0);
    bf16x8 b0l = *(const bf16x8*)(wlo + bo0);
    bf16x8 b1h = *(const bf16x8*)(whi + bo1);
    bf16x8 b1l = *(const bf16x8*)(wlo + bo1);

    // hi*hi
    acc[0][0] = __builtin_amdgcn_mfma_f32_16x16x32_bf16(a0h, b0h, acc[0][0], 0, 0, 0);
    acc[0][1] = __builtin_amdgcn_mfma_f32_16x16x32_bf16(a0h, b1h, acc[0][1], 0, 0, 0);
    acc[1][0] = __builtin_amdgcn_mfma_f32_16x16x32_bf16(a1h, b0h, acc[1][0], 0, 0, 0);
    acc[1][1] = __builtin_amdgcn_mfma_f32_16x16x32_bf16(a1h, b1h, acc[1][1], 0, 0, 0);
    acc[2][0] = __builtin_amdgcn_mfma_f32_16x16x32_bf16(a2h, b0h, acc[2][0], 0, 0, 0);
    acc[2][1] = __builtin_amdgcn_mfma_f32_16x16x32_bf16(a2h, b1h, acc[2][1], 0, 0, 0);
    // hi*lo
    acc[0][0] = __builtin_amdgcn_mfma_f32_16x16x32_bf16(a0h, b0l, acc[0][0], 0, 0, 0);
    acc[0][1] = __builtin_amdgcn_mfma_f32_16x16x32_bf16(a0h, b1l, acc[0][1], 0, 0, 0);
    acc[1][0] = __builtin_amdgcn_mfma_f32_16x16x32_bf16(a1h, b0l, acc[1][0], 0, 0, 0);
    acc[1][1] = __builtin_amdgcn_mfma_f32_16x16x32_bf16(a1h, b1l, acc[1][1], 0, 0, 0);
    acc[2][0] = __builtin_amdgcn_mfma_f32_16x16x32_bf16(a2h, b0l, acc[2][0], 0, 0, 0);
    acc[2][1] = __builtin_amdgcn_mfma_f32_16x16x32_bf16(a2h, b1l, acc[2][1], 0, 0, 0);
    // lo*hi
    acc[0][0] = __builtin_amdgcn_mfma_f32_16x16x32_bf16(a0l, b0h, acc[0][0], 0, 0, 0);
    acc[0][1] = __builtin_amdgcn_mfma_f32_16x16x32_bf16(a0l, b1h, acc[0][1], 0, 0, 0);
    acc[1][0] = __builtin_amdgcn_mfma_f32_16x16x32_bf16(a1l, b0h, acc[1][0], 0, 0, 0);
    acc[1][1] = __builtin_amdgcn_mfma_f32_16x16x32_bf16(a1l, b1h, acc[1][1], 0, 0, 0);
    acc[2][0] = __builtin_amdgcn_mfma_f32_16x16x32_bf16(a2l, b0h, acc[2][0], 0, 0, 0);
    acc[2][1] = __builtin_amdgcn_mfma_f32_16x16x32_bf16(a2l, b1h, acc[2][1], 0, 0, 0);
  }

  // Epilogue: bias + relu + per-capsule L2-normalize (16-lane reduce), store to LDS.
#pragma unroll
  for (int jn = 0; jn < 2; ++jn) {
    const int nt = jn ? nt1 : nt0;
    const int col = nt * 16 + ml;
    const float bias = isf32 ? ((const float*)b1)[col]
                             : bf16bits_to_f32(((const unsigned short*)b1)[col]);
#pragma unroll
    for (int mt = 0; mt < 3; ++mt) {
#pragma unroll
      for (int r = 0; r < 4; ++r) {
        const int row = mt * 16 + q * 4 + r;
        float v = fmaxf(acc[mt][jn][r] + bias, 0.f);
        float ss = v * v;  // reduce over the 16 lanes of this quad = capsule dims
        ss += __shfl_xor(ss, 1);
        ss += __shfl_xor(ss, 2);
        ss += __shfl_xor(ss, 4);
        ss += __shfl_xor(ss, 8);
        float rn = 1.f / fmaxf(sqrtf(ss), 1e-12f);
        if (row < 33) zn[row * ZSTRIDE + col] = v * rn;
      }
    }
  }
  __syncthreads();

  // ---------------- Routing (3 iterations, u in registers of threads 0..127) ----
  float u = 0.f;
  if (tid < 128) {
    float s = 0.f;
#pragma unroll 8
    for (int n = 0; n < 32; ++n) s += zn[n * ZSTRIDE + tid];
    u = s * 0.125f + zn[32 * ZSTRIDE + tid];  // iter0: softmax(0) = 1/8 uniform
    float ss = u * u;
    ss += __shfl_xor(ss, 1);
    ss += __shfl_xor(ss, 2);
    ss += __shfl_xor(ss, 4);
    ss += __shfl_xor(ss, 8);
    u *= 1.f / fmaxf(sqrtf(ss), 1e-12f);
  }

#pragma unroll
  for (int it = 1; it < 3; ++it) {
    if (tid < 128) {
      const int kk = tid >> 4;
#pragma unroll 4
      for (int n = 0; n < 32; ++n) {
        float prod = zn[n * ZSTRIDE + tid] * u;
        prod += __shfl_xor(prod, 1);
        prod += __shfl_xor(prod, 2);
        prod += __shfl_xor(prod, 4);
        prod += __shfl_xor(prod, 8);
        if ((tid & 15) == 0) pl[n * 8 + kk] = prod;
      }
    }
    __syncthreads();
    {  // softmax over k (8-lane groups), one thread per (n,k)
      float v = pl[tid];
      float m = v;
      m = fmaxf(m, __shfl_xor(m, 1));
      m = fmaxf(m, __shfl_xor(m, 2));
      m = fmaxf(m, __shfl_xor(m, 4));
      float e = __expf(v - m);
      float sden = e;
      sden += __shfl_xor(sden, 1);
      sden += __shfl_xor(sden, 2);
      sden += __shfl_xor(sden, 4);
      pl[tid] = e / sden;
    }
    __syncthreads();
    if (tid < 128) {
      const int kk = tid >> 4;
      float unew = 0.f;
#pragma unroll 8
      for (int n = 0; n < 32; ++n) unew += pl[n * 8 + kk] * zn[n * ZSTRIDE + tid];
      unew += zn[32 * ZSTRIDE + tid];
      if (it < 2) {
        float ss = unew * unew;
        ss += __shfl_xor(ss, 1);
        ss += __shfl_xor(ss, 2);
        ss += __shfl_xor(ss, 4);
        ss += __shfl_xor(ss, 8);
        unew *= 1.f / fmaxf(sqrtf(ss), 1e-12f);
      }
      u = unew;
    }
    __syncthreads();
  }

  if (tid < 128) {
    float r = (u < 0.f) ? 0.f : u;
    const size_t oidx = bs * DD + tid;
    if (isf32) {
      ((float*)out)[oidx] = r;
    } else {
      unsigned int xb = __float_as_uint(r);
      unsigned int l = (xb >> 16) & 1u;
      ((unsigned short*)out)[oidx] = (unsigned short)((xb + 0x7fffu + l) >> 16);
    }
  }
}

extern "C" void kernel_launch(void* const* d_in, const int* in_sizes, int n_in,
                              void* d_out, int out_size, void* d_ws, size_t ws_size,
                              hipStream_t stream) {
  (void)in_sizes; (void)n_in; (void)out_size; (void)ws_size;
  const void* selfv = d_in[0];   // [128,64,128]
  const void* neighv = d_in[1];  // [128,64,32,128]
  const void* w1 = d_in[2];      // [128,128]
  const void* b1 = d_in[3];      // [128]
  // d_in[4] = max_iter (always 3) — hardcoded.
  int* flag = (int*)d_ws;
  unsigned short* whi = (unsigned short*)((char*)d_ws + 64);           // 32 KB
  unsigned short* wlo = (unsigned short*)((char*)d_ws + 64 + 32768);   // 32 KB

  detect_kernel<<<1, 64, 0, stream>>>((const unsigned short*)w1, flag);
  swizzle_w_kernel<<<64, 256, 0, stream>>>(w1, flag, whi, wlo);
  routing_kernel<<<8192, 256, 0, stream>>>(selfv, neighv, whi, wlo, b1, d_out, flag);
}

// Round 4
// 284.657 us; speedup vs baseline: 1.3015x; 1.3015x over previous
//
#include <hip/hip_runtime.h>
#include <hip/hip_bf16.h>

// RoutingLayer: B=128,S=64,N=32, D=128, K=8 capsules x C=16, 3 routing iters.
// fp32 inputs, split-bf16 MFMA GEMM (hi*hi + hi*lo + lo*hi), fused routing.
// R4: routing rewritten — all 256 threads, flat serial dots, no shuffle chains
// in hot loops; normalization factored into nrm[] (read-time fold).

#define NB 32
#define DD 128
#define ZS 132    // zn row stride (floats), pad vs 128
#define PPS 33    // pp row stride
#define PARTS 132 // part row stride

typedef __attribute__((ext_vector_type(8))) short bf16x8;
typedef __attribute__((ext_vector_type(4))) float f32x4;
typedef __attribute__((ext_vector_type(4))) float float4v;

__device__ __forceinline__ float bf16bits_to_f32(unsigned short u) {
  return __uint_as_float(((unsigned int)u) << 16);
}
__device__ __forceinline__ void split_bf16(float x, short& hi, short& lo) {
  unsigned int xb = __float_as_uint(x);
  hi = (short)(xb >> 16);
  float hif = __uint_as_float(xb & 0xFFFF0000u);
  float lof = x - hif;  // exact
  lo = (short)(__float_as_uint(lof) >> 16);
}

__global__ void detect_kernel(const unsigned short* __restrict__ w1u,
                              int* __restrict__ flag) {
  int t = threadIdx.x;
  float v = bf16bits_to_f32(w1u[2 * t]);
  int hit = !(fabsf(v) < 1e4f);
  unsigned long long m = __ballot(hit);
  if (t == 0) flag[0] = (m != 0ull) ? 1 : 0;
}

// W (k-major 128x128) -> MFMA-B fragment-major hi/lo bf16.
__global__ __launch_bounds__(256) void swizzle_w_kernel(
    const void* __restrict__ w1, const int* __restrict__ flag,
    unsigned short* __restrict__ whi, unsigned short* __restrict__ wlo) {
  int idx = blockIdx.x * 256 + threadIdx.x;
  int k = idx >> 7, n = idx & 127;
  int kt = k >> 5, q = (k >> 3) & 3, j = k & 7;
  int nt = n >> 4, nl = n & 15;
  int lane = q * 16 + nl;
  int dst = ((kt * 8 + nt) * 64 + lane) * 8 + j;
  short hb, lb;
  if (*flag) {
    split_bf16(((const float*)w1)[idx], hb, lb);
  } else {
    hb = (short)((const unsigned short*)w1)[idx];
    lb = 0;
  }
  whi[dst] = (unsigned short)hb;
  wlo[dst] = (unsigned short)lb;
}

__device__ __forceinline__ void load_frag2(const void* base, size_t elt_off,
                                           bool isf32, bf16x8& hi, bf16x8& lo) {
  if (!isf32) {
    hi = *(const bf16x8*)((const unsigned short*)base + elt_off);
#pragma unroll
    for (int i = 0; i < 8; ++i) lo[i] = 0;
    return;
  }
  const float* p = (const float*)base + elt_off;
  float4v v0 = *(const float4v*)p;
  float4v v1 = *(const float4v*)(p + 4);
#pragma unroll
  for (int i = 0; i < 4; ++i) {
    short h, l;
    split_bf16(v0[i], h, l);
    hi[i] = h; lo[i] = l;
    split_bf16(v1[i], h, l);
    hi[4 + i] = h; lo[4 + i] = l;
  }
}

__global__ __launch_bounds__(256) void routing_kernel(
    const void* __restrict__ selfv,
    const void* __restrict__ neighv,
    const unsigned short* __restrict__ whi,
    const unsigned short* __restrict__ wlo,
    const void* __restrict__ b1,
    void* __restrict__ out,
    const int* __restrict__ flag) {
  __shared__ __align__(16) float zn[33 * ZS];    // RAW relu'd GEMM output
  __shared__ __align__(16) float nrm[264];       // 1/||capsule|| per (row,k)
  __shared__ __align__(16) float pp[8 * PPS];    // prob * nrm, [k][n]
  __shared__ __align__(16) float part[8 * PARTS];// pass2 partials [oct][k*16+c..]
  __shared__ __align__(16) float uu[128];        // current u

  const int tid = threadIdx.x;
  const int lane = tid & 63;
  const int wv = tid >> 6;
  const int q = lane >> 4;
  const int ml = lane & 15;
  const size_t bs = blockIdx.x;
  const bool isf32 = (*flag != 0);

  const size_t noff = bs * (size_t)(NB * DD);
  const size_t soff = bs * (size_t)DD;
  const char* nbase = isf32 ? (const char*)((const float*)neighv + noff)
                            : (const char*)((const unsigned short*)neighv + noff);
  const char* sbase = isf32 ? (const char*)((const float*)selfv + soff)
                            : (const char*)((const unsigned short*)selfv + soff);

  // ---------------- GEMM: Z[48x128] = X[48x128] @ W[128x128], split-bf16 ------
  f32x4 acc[3][2];
#pragma unroll
  for (int mt = 0; mt < 3; ++mt)
#pragma unroll
    for (int jn = 0; jn < 2; ++jn) acc[mt][jn] = (f32x4){0.f, 0.f, 0.f, 0.f};

  const int nt0 = wv, nt1 = wv + 4;

#pragma unroll
  for (int kt = 0; kt < 4; ++kt) {
    const int koff = kt * 32 + q * 8;
    bf16x8 a0h, a0l, a1h, a1l, a2h, a2l;
    load_frag2(nbase, (size_t)ml * DD + koff, isf32, a0h, a0l);
    load_frag2(nbase, (size_t)(16 + ml) * DD + koff, isf32, a1h, a1l);
    load_frag2(sbase, (size_t)koff, isf32, a2h, a2l);
    const size_t bo0 = ((size_t)(kt * 8 + nt0) * 64 + lane) * 8;
    const size_t bo1 = ((size_t)(kt * 8 + nt1) * 64 + lane) * 8;
    bf16x8 b0h = *(const bf16x8*)(whi + bo0);
    bf16x8 b0l = *(const bf16x8*)(wlo + bo0);
    bf16x8 b1h = *(const bf16x8*)(whi + bo1);
    bf16x8 b1l = *(const bf16x8*)(wlo + bo1);

    acc[0][0] = __builtin_amdgcn_mfma_f32_16x16x32_bf16(a0h, b0h, acc[0][0], 0, 0, 0);
    acc[0][1] = __builtin_amdgcn_mfma_f32_16x16x32_bf16(a0h, b1h, acc[0][1], 0, 0, 0);
    acc[1][0] = __builtin_amdgcn_mfma_f32_16x16x32_bf16(a1h, b0h, acc[1][0], 0, 0, 0);
    acc[1][1] = __builtin_amdgcn_mfma_f32_16x16x32_bf16(a1h, b1h, acc[1][1], 0, 0, 0);
    acc[2][0] = __builtin_amdgcn_mfma_f32_16x16x32_bf16(a2h, b0h, acc[2][0], 0, 0, 0);
    acc[2][1] = __builtin_amdgcn_mfma_f32_16x16x32_bf16(a2h, b1h, acc[2][1], 0, 0, 0);
    acc[0][0] = __builtin_amdgcn_mfma_f32_16x16x32_bf16(a0h, b0l, acc[0][0], 0, 0, 0);
    acc[0][1] = __builtin_amdgcn_mfma_f32_16x16x32_bf16(a0h, b1l, acc[0][1], 0, 0, 0);
    acc[1][0] = __builtin_amdgcn_mfma_f32_16x16x32_bf16(a1h, b0l, acc[1][0], 0, 0, 0);
    acc[1][1] = __builtin_amdgcn_mfma_f32_16x16x32_bf16(a1h, b1l, acc[1][1], 0, 0, 0);
    acc[2][0] = __builtin_amdgcn_mfma_f32_16x16x32_bf16(a2h, b0l, acc[2][0], 0, 0, 0);
    acc[2][1] = __builtin_amdgcn_mfma_f32_16x16x32_bf16(a2h, b1l, acc[2][1], 0, 0, 0);
    acc[0][0] = __builtin_amdgcn_mfma_f32_16x16x32_bf16(a0l, b0h, acc[0][0], 0, 0, 0);
    acc[0][1] = __builtin_amdgcn_mfma_f32_16x16x32_bf16(a0l, b1h, acc[0][1], 0, 0, 0);
    acc[1][0] = __builtin_amdgcn_mfma_f32_16x16x32_bf16(a1l, b0h, acc[1][0], 0, 0, 0);
    acc[1][1] = __builtin_amdgcn_mfma_f32_16x16x32_bf16(a1l, b1h, acc[1][1], 0, 0, 0);
    acc[2][0] = __builtin_amdgcn_mfma_f32_16x16x32_bf16(a2l, b0h, acc[2][0], 0, 0, 0);
    acc[2][1] = __builtin_amdgcn_mfma_f32_16x16x32_bf16(a2l, b1h, acc[2][1], 0, 0, 0);
  }

  // Epilogue: bias + relu -> RAW zn in LDS (no normalization here).
#pragma unroll
  for (int jn = 0; jn < 2; ++jn) {
    const int nt = jn ? nt1 : nt0;
    const int col = nt * 16 + ml;
    const float bias = isf32 ? ((const float*)b1)[col]
                             : bf16bits_to_f32(((const unsigned short*)b1)[col]);
#pragma unroll
    for (int mt = 0; mt < 3; ++mt) {
#pragma unroll
      for (int r = 0; r < 4; ++r) {
        const int row = mt * 16 + q * 4 + r;
        float v = fmaxf(acc[mt][jn][r] + bias, 0.f);
        if (row < 33) zn[row * ZS + col] = v;
      }
    }
  }
  __syncthreads();

  // Norms per (row,k) capsule; also seed pp for iter 0 (uniform p = 1/8).
  for (int id = tid; id < 264; id += 256) {
    const int row = id >> 3, k = id & 7;
    const float4v* zp = (const float4v*)&zn[row * ZS + k * 16];
    float4v a = zp[0], b = zp[1], c = zp[2], d = zp[3];
    float ss = a[0]*a[0]+a[1]*a[1]+a[2]*a[2]+a[3]*a[3]
             + b[0]*b[0]+b[1]*b[1]+b[2]*b[2]+b[3]*b[3]
             + c[0]*c[0]+c[1]*c[1]+c[2]*c[2]+c[3]*c[3]
             + d[0]*d[0]+d[1]*d[1]+d[2]*d[2]+d[3]*d[3];
    float nv = 1.f / fmaxf(sqrtf(ss), 1e-12f);
    nrm[id] = nv;
    if (row < 32) pp[k * PPS + row] = nv * 0.125f;
  }
  __syncthreads();

  // ---------------- Routing: 3 iterations ----------------
  for (int it = 0; it < 3; ++it) {
    if (it > 0) {
      // pass1: logits per (n,k), softmax over k, store prob*nrm into pp[k][n].
      const int n = tid >> 3, k = tid & 7;
      const float4v* up = (const float4v*)&uu[k * 16];
      float4v u0 = up[0], u1 = up[1], u2 = up[2], u3 = up[3];
      const float4v* zp = (const float4v*)&zn[n * ZS + k * 16];
      float4v z0 = zp[0], z1 = zp[1], z2 = zp[2], z3 = zp[3];
      float dot = u0[0]*z0[0]+u0[1]*z0[1]+u0[2]*z0[2]+u0[3]*z0[3]
                + u1[0]*z1[0]+u1[1]*z1[1]+u1[2]*z1[2]+u1[3]*z1[3]
                + u2[0]*z2[0]+u2[1]*z2[1]+u2[2]*z2[2]+u2[3]*z2[3]
                + u3[0]*z3[0]+u3[1]*z3[1]+u3[2]*z3[2]+u3[3]*z3[3];
      const float nv = nrm[tid >> 3 << 3 | k];  // nrm[n*8+k] == nrm[tid]
      float logit = dot * nv;                    // TAU = 1
      float m = logit;
      m = fmaxf(m, __shfl_xor(m, 1));
      m = fmaxf(m, __shfl_xor(m, 2));
      m = fmaxf(m, __shfl_xor(m, 4));
      float e = __expf(logit - m);
      float s = e;
      s += __shfl_xor(s, 1);
      s += __shfl_xor(s, 2);
      s += __shfl_xor(s, 4);
      pp[k * PPS + n] = (e / s) * nv;
      __syncthreads();
    }
    // pass2: thread (q4=tid>>6, k2=(tid>>3)&7, oct=tid&7): partial weighted sums.
    {
      const int q4 = tid >> 6, k2 = (tid >> 3) & 7, oct = tid & 7;
      float4v a2 = (float4v){0.f, 0.f, 0.f, 0.f};
#pragma unroll
      for (int j = 0; j < 4; ++j) {
        const int n = oct + 8 * j;
        const float w = pp[k2 * PPS + n];
        float4v z = *(const float4v*)&zn[n * ZS + k2 * 16 + q4 * 4];
        a2[0] += w * z[0];
        a2[1] += w * z[1];
        a2[2] += w * z[2];
        a2[3] += w * z[3];
      }
      *(float4v*)&part[oct * PARTS + k2 * 16 + q4 * 4] = a2;
    }
    __syncthreads();
    // combine partials + self term; normalize (except last); write uu / output.
    if (tid < 128) {
      const int k = tid >> 4;
      float s = 0.f;
#pragma unroll
      for (int o = 0; o < 8; ++o) s += part[o * PARTS + tid];
      s += nrm[256 + k] * zn[32 * ZS + tid];  // self capsule (row 32)
      if (it < 2) {
        float ss = s * s;
        ss += __shfl_xor(ss, 1);
        ss += __shfl_xor(ss, 2);
        ss += __shfl_xor(ss, 4);
        ss += __shfl_xor(ss, 8);
        s *= 1.f / fmaxf(sqrtf(ss), 1e-12f);
        uu[tid] = s;
      } else {
        float r = (s < 0.f) ? 0.f : s;
        const size_t oidx = bs * DD + tid;
        if (isf32) {
          ((float*)out)[oidx] = r;
        } else {
          unsigned int xb = __float_as_uint(r);
          unsigned int l = (xb >> 16) & 1u;
          ((unsigned short*)out)[oidx] = (unsigned short)((xb + 0x7fffu + l) >> 16);
        }
      }
    }
    __syncthreads();
  }
}

extern "C" void kernel_launch(void* const* d_in, const int* in_sizes, int n_in,
                              void* d_out, int out_size, void* d_ws, size_t ws_size,
                              hipStream_t stream) {
  (void)in_sizes; (void)n_in; (void)out_size; (void)ws_size;
  const void* selfv = d_in[0];
  const void* neighv = d_in[1];
  const void* w1 = d_in[2];
  const void* b1 = d_in[3];
  int* flag = (int*)d_ws;
  unsigned short* whi = (unsigned short*)((char*)d_ws + 64);
  unsigned short* wlo = (unsigned short*)((char*)d_ws + 64 + 32768);

  detect_kernel<<<1, 64, 0, stream>>>((const unsigned short*)w1, flag);
  swizzle_w_kernel<<<64, 256, 0, stream>>>(w1, flag, whi, wlo);
  routing_kernel<<<8192, 256, 0, stream>>>(selfv, neighv, whi, wlo, b1, d_out, flag);
}

// Round 5
// 235.478 us; speedup vs baseline: 1.5734x; 1.2088x over previous
//
#include <hip/hip_runtime.h>
#include <hip/hip_bf16.h>

// RoutingLayer: B=128,S=64,N=32, D=128, K=8 capsules x C=16, 3 routing iters.
// fp32 inputs, split-bf16 MFMA GEMM (hi*hi + hi*lo + lo*hi), fused routing.
// R5: cooperative A-staging (convert fp32->hi/lo bf16 ONCE per block into LDS,
// ~6x less split VALU), GEMM frags via ds_read_b128, zn unions staging region,
// pass2 rewritten (256 threads, no part[] array) -> 20.7 KB LDS, 7 blocks/CU.

#define NB 32
#define DD 128
#define ZS 132   // zn row stride (floats)
#define PPS 37   // pp row stride (floats) — kills diagonal write conflicts
#define AST 136  // staged A row stride (bf16 units) = 272 B, 16B-aligned

// LDS layout (bytes):
// [0, 8976)      Ahi 33x136 bf16   } union with [0,17424) zn fp32 33x132
// [8976, 17952)  Alo 33x136 bf16   }
// [17952, 19008) nrm 264 f32
// [19008, 20192) pp  8x37 f32
// [20192, 20704) uu  128 f32
#define SMEM_BYTES 20704
#define ALO_OFF_SH 4488
#define NRM_OFF_F 4488
#define PP_OFF_F 4752
#define UU_OFF_F 5048

typedef __attribute__((ext_vector_type(8))) short bf16x8;
typedef __attribute__((ext_vector_type(4))) float f32x4;
typedef __attribute__((ext_vector_type(4))) float float4v;
typedef __attribute__((ext_vector_type(2))) unsigned int uint2v;

__device__ __forceinline__ float bf16bits_to_f32(unsigned short u) {
  return __uint_as_float(((unsigned int)u) << 16);
}
__device__ __forceinline__ void split_bf16(float x, unsigned short& hi, unsigned short& lo) {
  unsigned int xb = __float_as_uint(x);
  hi = (unsigned short)(xb >> 16);
  float hif = __uint_as_float(xb & 0xFFFF0000u);
  float lof = x - hif;  // exact
  lo = (unsigned short)(__float_as_uint(lof) >> 16);
}

__global__ void detect_kernel(const unsigned short* __restrict__ w1u,
                              int* __restrict__ flag) {
  int t = threadIdx.x;
  float v = bf16bits_to_f32(w1u[2 * t]);
  int hit = !(fabsf(v) < 1e4f);
  unsigned long long m = __ballot(hit);
  if (t == 0) flag[0] = (m != 0ull) ? 1 : 0;
}

// W (k-major 128x128) -> MFMA-B fragment-major hi/lo bf16.
__global__ __launch_bounds__(256) void swizzle_w_kernel(
    const void* __restrict__ w1, const int* __restrict__ flag,
    unsigned short* __restrict__ whi, unsigned short* __restrict__ wlo) {
  int idx = blockIdx.x * 256 + threadIdx.x;
  int k = idx >> 7, n = idx & 127;
  int kt = k >> 5, q = (k >> 3) & 3, j = k & 7;
  int nt = n >> 4, nl = n & 15;
  int lane = q * 16 + nl;
  int dst = ((kt * 8 + nt) * 64 + lane) * 8 + j;
  unsigned short hb, lb;
  if (*flag) {
    split_bf16(((const float*)w1)[idx], hb, lb);
  } else {
    hb = ((const unsigned short*)w1)[idx];
    lb = 0;
  }
  whi[dst] = hb;
  wlo[dst] = lb;
}

__global__ __launch_bounds__(256) void routing_kernel(
    const void* __restrict__ selfv,
    const void* __restrict__ neighv,
    const unsigned short* __restrict__ whi,
    const unsigned short* __restrict__ wlo,
    const void* __restrict__ b1,
    void* __restrict__ out,
    const int* __restrict__ flag) {
  __shared__ __align__(16) unsigned char smem[SMEM_BYTES];
  unsigned short* Ahi = (unsigned short*)smem;
  unsigned short* Alo = Ahi + ALO_OFF_SH;
  float* zn = (float*)smem;  // union: valid after GEMM
  float* nrm = (float*)smem + NRM_OFF_F;
  float* pp = (float*)smem + PP_OFF_F;
  float* uu = (float*)smem + UU_OFF_F;

  const int tid = threadIdx.x;
  const int lane = tid & 63;
  const int wv = tid >> 6;
  const int q = lane >> 4;
  const int ml = lane & 15;
  const size_t bs = blockIdx.x;
  const bool isf32 = (*flag != 0);

  const size_t noff = bs * (size_t)(NB * DD);
  const size_t soff = bs * (size_t)DD;

  // ---------------- Stage A (33x128) into LDS as hi/lo bf16, convert ONCE ----
  if (isf32) {
    const float* nf = (const float*)neighv + noff;
    const float* sf = (const float*)selfv + soff;
#pragma unroll
    for (int i = 0; i < 4; ++i) {
      int f = tid + (i << 8);  // float4 index 0..1023
      int r = f >> 5, c4 = f & 31;
      float4v v = ((const float4v*)nf)[f];
      unsigned short h0, h1, h2, h3, l0, l1, l2, l3;
      split_bf16(v[0], h0, l0);
      split_bf16(v[1], h1, l1);
      split_bf16(v[2], h2, l2);
      split_bf16(v[3], h3, l3);
      uint2v hw = (uint2v){(unsigned int)h0 | ((unsigned int)h1 << 16),
                           (unsigned int)h2 | ((unsigned int)h3 << 16)};
      uint2v lw = (uint2v){(unsigned int)l0 | ((unsigned int)l1 << 16),
                           (unsigned int)l2 | ((unsigned int)l3 << 16)};
      *(uint2v*)(Ahi + r * AST + c4 * 4) = hw;
      *(uint2v*)(Alo + r * AST + c4 * 4) = lw;
    }
    if (tid < 32) {
      float4v v = ((const float4v*)sf)[tid];
      unsigned short h0, h1, h2, h3, l0, l1, l2, l3;
      split_bf16(v[0], h0, l0);
      split_bf16(v[1], h1, l1);
      split_bf16(v[2], h2, l2);
      split_bf16(v[3], h3, l3);
      uint2v hw = (uint2v){(unsigned int)h0 | ((unsigned int)h1 << 16),
                           (unsigned int)h2 | ((unsigned int)h3 << 16)};
      uint2v lw = (uint2v){(unsigned int)l0 | ((unsigned int)l1 << 16),
                           (unsigned int)l2 | ((unsigned int)l3 << 16)};
      *(uint2v*)(Ahi + 32 * AST + tid * 4) = hw;
      *(uint2v*)(Alo + 32 * AST + tid * 4) = lw;
    }
  } else {
    const unsigned short* nbf = (const unsigned short*)neighv + noff;
    const unsigned short* sbf = (const unsigned short*)selfv + soff;
    const bf16x8 zv = (bf16x8){0, 0, 0, 0, 0, 0, 0, 0};
#pragma unroll
    for (int i = 0; i < 2; ++i) {
      int s = tid + (i << 8);  // 16B chunk 0..511
      int r = s >> 4, c8 = s & 15;
      bf16x8 v = *(const bf16x8*)(nbf + r * DD + c8 * 8);
      *(bf16x8*)(Ahi + r * AST + c8 * 8) = v;
      *(bf16x8*)(Alo + r * AST + c8 * 8) = zv;
    }
    if (tid < 16) {
      bf16x8 v = *(const bf16x8*)(sbf + tid * 8);
      *(bf16x8*)(Ahi + 32 * AST + tid * 8) = v;
      *(bf16x8*)(Alo + 32 * AST + tid * 8) = zv;
    }
  }
  __syncthreads();

  // ---------------- GEMM: Z[48x128] = X @ W, split-bf16, frags from LDS ------
  f32x4 acc[3][2];
#pragma unroll
  for (int mt = 0; mt < 3; ++mt)
#pragma unroll
    for (int jn = 0; jn < 2; ++jn) acc[mt][jn] = (f32x4){0.f, 0.f, 0.f, 0.f};

  const int nt0 = wv, nt1 = wv + 4;

#pragma unroll
  for (int kt = 0; kt < 4; ++kt) {
    const int fo = kt * 32 + q * 8;
    bf16x8 a0h = *(const bf16x8*)(Ahi + ml * AST + fo);
    bf16x8 a0l = *(const bf16x8*)(Alo + ml * AST + fo);
    bf16x8 a1h = *(const bf16x8*)(Ahi + (16 + ml) * AST + fo);
    bf16x8 a1l = *(const bf16x8*)(Alo + (16 + ml) * AST + fo);
    bf16x8 a2h = *(const bf16x8*)(Ahi + 32 * AST + fo);  // broadcast row
    bf16x8 a2l = *(const bf16x8*)(Alo + 32 * AST + fo);
    const size_t bo0 = ((size_t)(kt * 8 + nt0) * 64 + lane) * 8;
    const size_t bo1 = ((size_t)(kt * 8 + nt1) * 64 + lane) * 8;
    bf16x8 b0h = *(const bf16x8*)(whi + bo0);
    bf16x8 b0l = *(const bf16x8*)(wlo + bo0);
    bf16x8 b1h = *(const bf16x8*)(whi + bo1);
    bf16x8 b1l = *(const bf16x8*)(wlo + bo1);

    acc[0][0] = __builtin_amdgcn_mfma_f32_16x16x32_bf16(a0h, b0h, acc[0][0], 0, 0, 0);
    acc[0][1] = __builtin_amdgcn_mfma_f32_16x16x32_bf16(a0h, b1h, acc[0][1], 0, 0, 0);
    acc[1][0] = __builtin_amdgcn_mfma_f32_16x16x32_bf16(a1h, b0h, acc[1][0], 0, 0, 0);
    acc[1][1] = __builtin_amdgcn_mfma_f32_16x16x32_bf16(a1h, b1h, acc[1][1], 0, 0, 0);
    acc[2][0] = __builtin_amdgcn_mfma_f32_16x16x32_bf16(a2h, b0h, acc[2][0], 0, 0, 0);
    acc[2][1] = __builtin_amdgcn_mfma_f32_16x16x32_bf16(a2h, b1h, acc[2][1], 0, 0, 0);
    acc[0][0] = __builtin_amdgcn_mfma_f32_16x16x32_bf16(a0h, b0l, acc[0][0], 0, 0, 0);
    acc[0][1] = __builtin_amdgcn_mfma_f32_16x16x32_bf16(a0h, b1l, acc[0][1], 0, 0, 0);
    acc[1][0] = __builtin_amdgcn_mfma_f32_16x16x32_bf16(a1h, b0l, acc[1][0], 0, 0, 0);
    acc[1][1] = __builtin_amdgcn_mfma_f32_16x16x32_bf16(a1h, b1l, acc[1][1], 0, 0, 0);
    acc[2][0] = __builtin_amdgcn_mfma_f32_16x16x32_bf16(a2h, b0l, acc[2][0], 0, 0, 0);
    acc[2][1] = __builtin_amdgcn_mfma_f32_16x16x32_bf16(a2h, b1l, acc[2][1], 0, 0, 0);
    acc[0][0] = __builtin_amdgcn_mfma_f32_16x16x32_bf16(a0l, b0h, acc[0][0], 0, 0, 0);
    acc[0][1] = __builtin_amdgcn_mfma_f32_16x16x32_bf16(a0l, b1h, acc[0][1], 0, 0, 0);
    acc[1][0] = __builtin_amdgcn_mfma_f32_16x16x32_bf16(a1l, b0h, acc[1][0], 0, 0, 0);
    acc[1][1] = __builtin_amdgcn_mfma_f32_16x16x32_bf16(a1l, b1h, acc[1][1], 0, 0, 0);
    acc[2][0] = __builtin_amdgcn_mfma_f32_16x16x32_bf16(a2l, b0h, acc[2][0], 0, 0, 0);
    acc[2][1] = __builtin_amdgcn_mfma_f32_16x16x32_bf16(a2l, b1h, acc[2][1], 0, 0, 0);
  }
  __syncthreads();  // all waves done reading Ahi/Alo before zn overwrites them

  // Epilogue: bias + relu -> RAW zn (fp32) over the staging region.
#pragma unroll
  for (int jn = 0; jn < 2; ++jn) {
    const int nt = jn ? nt1 : nt0;
    const int col = nt * 16 + ml;
    const float bias = isf32 ? ((const float*)b1)[col]
                             : bf16bits_to_f32(((const unsigned short*)b1)[col]);
#pragma unroll
    for (int mt = 0; mt < 3; ++mt) {
#pragma unroll
      for (int r = 0; r < 4; ++r) {
        const int row = mt * 16 + q * 4 + r;
        float v = fmaxf(acc[mt][jn][r] + bias, 0.f);
        if (row < 33) zn[row * ZS + col] = v;
      }
    }
  }
  __syncthreads();

  // Norms per (row,k); seed pp for iter 0 (uniform p=1/8, nrm folded).
  for (int id = tid; id < 264; id += 256) {
    const int row = id >> 3, k = id & 7;
    const float4v* zp = (const float4v*)&zn[row * ZS + k * 16];
    float4v a = zp[0], b = zp[1], c = zp[2], d = zp[3];
    float ss = a[0]*a[0]+a[1]*a[1]+a[2]*a[2]+a[3]*a[3]
             + b[0]*b[0]+b[1]*b[1]+b[2]*b[2]+b[3]*b[3]
             + c[0]*c[0]+c[1]*c[1]+c[2]*c[2]+c[3]*c[3]
             + d[0]*d[0]+d[1]*d[1]+d[2]*d[2]+d[3]*d[3];
    float nv = 1.f / fmaxf(sqrtf(ss), 1e-12f);
    nrm[id] = nv;
    if (row < 32) pp[k * PPS + row] = nv * 0.125f;
  }
  __syncthreads();

  // ---------------- Routing: 3 iterations ----------------
  const int k2 = tid >> 5, half = (tid >> 4) & 1, c2 = tid & 15;
  for (int it = 0; it < 3; ++it) {
    if (it > 0) {
      // pass1: logits per (n,k); softmax over k; pp[k][n] = prob * nrm[n,k].
      const int n1 = tid >> 3, k1 = tid & 7;
      const float4v* up = (const float4v*)&uu[k1 * 16];
      float4v u0 = up[0], u1 = up[1], u2 = up[2], u3 = up[3];
      const float4v* zp = (const float4v*)&zn[n1 * ZS + k1 * 16];
      float4v z0 = zp[0], z1 = zp[1], z2 = zp[2], z3 = zp[3];
      float dot = u0[0]*z0[0]+u0[1]*z0[1]+u0[2]*z0[2]+u0[3]*z0[3]
                + u1[0]*z1[0]+u1[1]*z1[1]+u1[2]*z1[2]+u1[3]*z1[3]
                + u2[0]*z2[0]+u2[1]*z2[1]+u2[2]*z2[2]+u2[3]*z2[3]
                + u3[0]*z3[0]+u3[1]*z3[1]+u3[2]*z3[2]+u3[3]*z3[3];
      const float nv = nrm[n1 * 8 + k1];
      float logit = dot * nv;  // TAU = 1
      float m = logit;
      m = fmaxf(m, __shfl_xor(m, 1));
      m = fmaxf(m, __shfl_xor(m, 2));
      m = fmaxf(m, __shfl_xor(m, 4));
      float e = __expf(logit - m);
      float s = e;
      s += __shfl_xor(s, 1);
      s += __shfl_xor(s, 2);
      s += __shfl_xor(s, 4);
      pp[k1 * PPS + n1] = (e / s) * nv;
      __syncthreads();
    }
    // pass2: 256 threads; (k2,c2) duplicated over half; each half sums 16 n's.
    float s = 0.f;
#pragma unroll
    for (int n0 = 0; n0 < 16; ++n0) {
      const int n = half * 16 + n0;
      s += pp[k2 * PPS + n] * zn[n * ZS + k2 * 16 + c2];
    }
    s += __shfl_xor(s, 16);                       // combine halves
    s += nrm[256 + k2] * zn[32 * ZS + k2 * 16 + c2];  // self capsule
    if (it < 2) {
      float ss = s * s;
      ss += __shfl_xor(ss, 1);
      ss += __shfl_xor(ss, 2);
      ss += __shfl_xor(ss, 4);
      ss += __shfl_xor(ss, 8);
      s *= 1.f / fmaxf(sqrtf(ss), 1e-12f);
      if (half == 0) uu[k2 * 16 + c2] = s;
    } else if (half == 0) {
      float r = (s < 0.f) ? 0.f : s;
      const size_t oidx = bs * DD + k2 * 16 + c2;
      if (isf32) {
        ((float*)out)[oidx] = r;
      } else {
        unsigned int xb = __float_as_uint(r);
        unsigned int l = (xb >> 16) & 1u;
        ((unsigned short*)out)[oidx] = (unsigned short)((xb + 0x7fffu + l) >> 16);
      }
    }
    __syncthreads();
  }
}

extern "C" void kernel_launch(void* const* d_in, const int* in_sizes, int n_in,
                              void* d_out, int out_size, void* d_ws, size_t ws_size,
                              hipStream_t stream) {
  (void)in_sizes; (void)n_in; (void)out_size; (void)ws_size;
  const void* selfv = d_in[0];
  const void* neighv = d_in[1];
  const void* w1 = d_in[2];
  const void* b1 = d_in[3];
  int* flag = (int*)d_ws;
  unsigned short* whi = (unsigned short*)((char*)d_ws + 64);
  unsigned short* wlo = (unsigned short*)((char*)d_ws + 64 + 32768);

  detect_kernel<<<1, 64, 0, stream>>>((const unsigned short*)w1, flag);
  swizzle_w_kernel<<<64, 256, 0, stream>>>(w1, flag, whi, wlo);
  routing_kernel<<<8192, 256, 0, stream>>>(selfv, neighv, whi, wlo, b1, d_out, flag);
}